// Round 6
// baseline (628.171 us; speedup 1.0000x reference)
//
#include <hip/hip_runtime.h>

#define NB 8
#define NN 10000
#define NE 320000
#define NF 128
#define NH 128

// ---------------- ws layout (float/int indices into ws) ----------------
// [0,        80000)    dinv    (NB*NN f32)
// [80000,   160000)    deg     (NB*NN i32)
// [160000,  160016)    flag    (i32 edge-dtype detect)
// [160016, 1440016)    mask    (NN*NH f32: 0.0 or 2.0)
// [1440016, 1520024)   offs    (NB*(NN+1) i32) CSR offsets per graph
// [1520024, 1600024)   cursor  (NB*NN i32)
// [1600024, 4160024)   csr     (NB*NE i32) source rows bucketed by dst
// [4160024, 14400024)  y = (X@W)*dinv[row]  (NB*NN*NH f32)

__device__ __forceinline__ int load_edge(const int* ei, size_t idx, int is64) {
    if (is64) return (int)(((const long long*)ei)[idx]);
    return ei[idx];
}

__global__ void detect_kernel(const int* __restrict__ ei, int* __restrict__ flag) {
    __shared__ int s;
    if (threadIdx.x == 0) s = 1;
    __syncthreads();
    int bad = 0;
    for (int q = threadIdx.x; q < 1024; q += 256)
        if (ei[2 * q + 1] != 0) bad = 1;
    if (bad) atomicAnd(&s, 0);
    __syncthreads();
    if (threadIdx.x == 0) *flag = s;   // 1 => int64 layout
}

// JAX threefry2x32, partitionable path: counter i -> (hi=0, lo=i), key (0,42),
// out = x0 ^ x1; keep <=> MSB==0; scale 2.0 (keep) else 0.0.
__global__ void mask_kernel(float* __restrict__ mask) {
    const unsigned TOT = NN * NH;
    unsigned i = blockIdx.x * 256 + threadIdx.x;
    if (i >= TOT) return;
    const unsigned ks0 = 0u, ks1 = 42u, ks2 = 0x1BD11BDAu ^ 0u ^ 42u;
    unsigned x0 = 0u + ks0;
    unsigned x1 = i + ks1;
#define TFR(r) { x0 += x1; x1 = (x1 << (r)) | (x1 >> (32 - (r))); x1 ^= x0; }
    TFR(13) TFR(15) TFR(26) TFR(6)
    x0 += ks1; x1 += ks2 + 1u;
    TFR(17) TFR(29) TFR(16) TFR(24)
    x0 += ks2; x1 += ks0 + 2u;
    TFR(13) TFR(15) TFR(26) TFR(6)
    x0 += ks0; x1 += ks1 + 3u;
    TFR(17) TFR(29) TFR(16) TFR(24)
    x0 += ks1; x1 += ks2 + 4u;
    TFR(13) TFR(15) TFR(26) TFR(6)
    x0 += ks2; x1 += ks0 + 5u;
#undef TFR
    unsigned bits = x0 ^ x1;
    mask[i] = (bits & 0x80000000u) ? 0.0f : 2.0f;
}

// XCD-local: blockIdx&7 = graph, so each graph's deg (40KB) stays in one L2.
__global__ __launch_bounds__(256) void deg_kernel(const int* __restrict__ ei,
                                                  const int* __restrict__ flag,
                                                  int* __restrict__ deg) {
    int b = blockIdx.x & 7;
    int e = (blockIdx.x >> 3) * 256 + threadIdx.x;
    if (e >= NE) return;
    int is64 = *flag;
    int col = load_edge(ei, (size_t)b * 2 * NE + NE + e, is64);
    atomicAdd(&deg[b * NN + col], 1);
}

__global__ __launch_bounds__(256) void dinv_kernel(const int* __restrict__ deg,
                                                   float* __restrict__ dinv) {
    int i = blockIdx.x * 256 + threadIdx.x;
    if (i >= NB * NN) return;
    dinv[i] = 1.0f / sqrtf((float)(deg[i] + 1));  // +1 self-loop
}

// Exclusive prefix scan of deg per graph -> offs (and cursor copy). 1 block/graph.
__global__ __launch_bounds__(1024) void scan_kernel(const int* __restrict__ deg,
                                                    int* __restrict__ offs,
                                                    int* __restrict__ cursor) {
    int b = blockIdx.x;
    __shared__ int s[1024];
    int t = threadIdx.x;
    int carry = 0;
    for (int c0 = 0; c0 < NN; c0 += 1024) {
        int i = c0 + t;
        int v = (i < NN) ? deg[b * NN + i] : 0;
        s[t] = v;
        __syncthreads();
        int x = v;
        for (int off = 1; off < 1024; off <<= 1) {
            int add = (t >= off) ? s[t - off] : 0;
            __syncthreads();
            x += add;
            s[t] = x;
            __syncthreads();
        }
        int tot = s[1023];
        if (i < NN) {
            int e = carry + x - v;       // exclusive
            offs[b * (NN + 1) + i] = e;
            cursor[b * NN + i] = e;
        }
        carry += tot;
        __syncthreads();
    }
    if (t == 0) offs[b * (NN + 1) + NN] = carry;
}

// Bucket-fill CSR, XCD-local. csr store via atomicExch: atomics execute AT the
// L2 and allocate the line there, so the ~32 scattered dword writes per 128B
// line combine into one writeback — plain store-misses were write-through
// partial lines (round-5 counter: WRITE_SIZE 100MB for 10MB csr, FETCH flat).
__global__ __launch_bounds__(256) void fill_kernel(const int* __restrict__ ei,
                                                   const int* __restrict__ flag,
                                                   int* __restrict__ cursor,
                                                   int* __restrict__ csr) {
    int b = blockIdx.x & 7;
    int e = (blockIdx.x >> 3) * 256 + threadIdx.x;
    if (e >= NE) return;
    int is64 = *flag;
    size_t base = (size_t)b * 2 * NE;
    int row = load_edge(ei, base + e, is64);
    int col = load_edge(ei, base + NE + e, is64);
    int pos = atomicAdd(&cursor[b * NN + col], 1);
    atomicExch(&csr[(size_t)b * NE + pos], row);
}

// y = (X @ W) * dinv[row].  blockIdx.x&7 = graph (XCD-local), >>3 = row block.
__global__ __launch_bounds__(256) void gemm_scale(const float* __restrict__ X,
                                                  const float* __restrict__ Wm,
                                                  const float* __restrict__ dinv,
                                                  float* __restrict__ y) {
    __shared__ float Xs[64][32];
    __shared__ float Ws[32][128];
    int b = blockIdx.x & 7;
    int row0 = (blockIdx.x >> 3) * 64;
    int t = threadIdx.x;
    int cg = t & 31;
    int rg = t >> 5;
    float acc[8][4] = {};
    const float* Xb = X + (size_t)b * NN * NF;

    for (int k0 = 0; k0 < NF; k0 += 32) {
        for (int q = t; q < 512; q += 256) {
            int r = q >> 3, c4 = q & 7;
            int gr = row0 + r;
            float4 v = make_float4(0.f, 0.f, 0.f, 0.f);
            if (gr < NN) v = *(const float4*)(Xb + (size_t)gr * NF + k0 + c4 * 4);
            *(float4*)&Xs[r][c4 * 4] = v;
        }
        for (int q = t; q < 1024; q += 256) {
            float4 v = *(const float4*)(Wm + k0 * NH + q * 4);
            *(float4*)(&Ws[0][0] + q * 4) = v;
        }
        __syncthreads();
#pragma unroll
        for (int kc = 0; kc < 32; kc += 4) {
            float4 xv[8];
#pragma unroll
            for (int i = 0; i < 8; ++i) xv[i] = *(const float4*)&Xs[rg * 8 + i][kc];
#pragma unroll
            for (int j = 0; j < 4; ++j) {
                float4 w = *(const float4*)&Ws[kc + j][cg * 4];
#pragma unroll
                for (int i = 0; i < 8; ++i) {
                    float xsv = (j == 0) ? xv[i].x : (j == 1) ? xv[i].y
                              : (j == 2) ? xv[i].z : xv[i].w;
                    acc[i][0] = fmaf(xsv, w.x, acc[i][0]);
                    acc[i][1] = fmaf(xsv, w.y, acc[i][1]);
                    acc[i][2] = fmaf(xsv, w.z, acc[i][2]);
                    acc[i][3] = fmaf(xsv, w.w, acc[i][3]);
                }
            }
        }
        __syncthreads();
    }
#pragma unroll
    for (int i = 0; i < 8; ++i) {
        int gr = row0 + rg * 8 + i;
        if (gr >= NN) continue;
        float d = dinv[b * NN + gr];
        float4 v = make_float4(acc[i][0] * d, acc[i][1] * d, acc[i][2] * d, acc[i][3] * d);
        *(float4*)(y + ((size_t)b * NN + gr) * NH + cg * 4) = v;
    }
}

// Gather-reduce over one 64-feature half. One wave per node.
// 4 edges/iter: sub = lane>>4 picks the edge, 16 lanes x float4 = 64 feats.
// blockIdx%8 = graph -> per-(graph,half) working set 2.56MB resident in XCD L2.
template<int LAYER>
__global__ __launch_bounds__(256) void aggregate_half(const float* __restrict__ y,
                                                      const int* __restrict__ offs,
                                                      const int* __restrict__ csr,
                                                      const float* __restrict__ dinv,
                                                      const float* __restrict__ bias,
                                                      const float* __restrict__ mask,
                                                      float* __restrict__ out,
                                                      int half) {
    int b = blockIdx.x & 7;
    int w = threadIdx.x >> 6;
    int n = (blockIdx.x >> 3) * 4 + w;       // 2500*4 = 10000 exact
    int lane = threadIdx.x & 63;
    int sub = lane >> 4;                      // which edge of the group of 4
    int f4 = (lane & 15) * 4 + half * 64;     // feature quad
    const float* yb = y + (size_t)b * NN * NH;
    int o0 = offs[b * (NN + 1) + n];
    int o1 = offs[b * (NN + 1) + n + 1];
    float4 acc = make_float4(0.f, 0.f, 0.f, 0.f);
    if (sub == 0) acc = *(const float4*)(yb + (size_t)n * NH + f4);   // self-loop once
    const int* csrb = csr + (size_t)b * NE;
    for (int base = o0; base < o1; base += 64) {
        int m = o1 - base; if (m > 64) m = 64;
        int r = (lane < m) ? csrb[base + lane] : 0;
        int mp = m & ~3;
#pragma unroll 4
        for (int jj = 0; jj < mp; jj += 4) {
            int row = __shfl(r, jj + sub);
            float4 v = *(const float4*)(yb + (size_t)row * NH + f4);
            acc.x += v.x; acc.y += v.y; acc.z += v.z; acc.w += v.w;
        }
        if (mp < m) {                          // wave-uniform tail (1..3 edges)
            int rem = m - mp;
            int row = __shfl(r, mp + (sub < rem ? sub : 0));
            float4 v = *(const float4*)(yb + (size_t)row * NH + f4);
            if (sub < rem) { acc.x += v.x; acc.y += v.y; acc.z += v.z; acc.w += v.w; }
        }
    }
    // combine the 4 edge-subsets (lanes L, L+16, L+32, L+48 share features)
    acc.x += __shfl_xor(acc.x, 16); acc.y += __shfl_xor(acc.y, 16);
    acc.z += __shfl_xor(acc.z, 16); acc.w += __shfl_xor(acc.w, 16);
    acc.x += __shfl_xor(acc.x, 32); acc.y += __shfl_xor(acc.y, 32);
    acc.z += __shfl_xor(acc.z, 32); acc.w += __shfl_xor(acc.w, 32);
    if (lane < 16) {
        float d = dinv[b * NN + n];
        float4 bi = *(const float4*)(bias + f4);
        float4 o;
        o.x = fmaf(d, acc.x, bi.x);
        o.y = fmaf(d, acc.y, bi.y);
        o.z = fmaf(d, acc.z, bi.z);
        o.w = fmaf(d, acc.w, bi.w);
        if (LAYER == 1) {
            float4 m4 = *(const float4*)(mask + (size_t)n * NH + f4);
            o.x = fmaxf(o.x, 0.f) * m4.x;
            o.y = fmaxf(o.y, 0.f) * m4.y;
            o.z = fmaxf(o.z, 0.f) * m4.z;
            o.w = fmaxf(o.w, 0.f) * m4.w;
        }
        *(float4*)(out + ((size_t)b * NN + n) * NH + f4) = o;
    }
}

extern "C" void kernel_launch(void* const* d_in, const int* in_sizes, int n_in,
                              void* d_out, int out_size, void* d_ws, size_t ws_size,
                              hipStream_t stream) {
    const float* xs = (const float*)d_in[0];
    const int*   ei = (const int*)d_in[1];
    const float* W1 = (const float*)d_in[2];
    const float* b1 = (const float*)d_in[3];
    const float* W2 = (const float*)d_in[4];
    const float* b2 = (const float*)d_in[5];
    float* out = (float*)d_out;

    float* ws     = (float*)d_ws;
    float* dinv   = ws;
    int*   deg    = (int*)(ws + 80000);
    int*   flag   = (int*)(ws + 160000);
    float* mask   = ws + 160016;
    int*   offs   = (int*)(ws + 1440016);
    int*   cursor = (int*)(ws + 1520024);
    int*   csr    = (int*)(ws + 1600024);
    float* y      = ws + 4160024;

    dim3 edge_grid(8 * ((NE + 255) / 256));  // blockIdx&7 = graph (XCD-local)

    hipMemsetAsync(deg, 0, (size_t)NB * NN * sizeof(int), stream);
    detect_kernel<<<1, 256, 0, stream>>>(ei, flag);
    mask_kernel<<<(NN * NH + 255) / 256, 256, 0, stream>>>(mask);
    deg_kernel<<<edge_grid, 256, 0, stream>>>(ei, flag, deg);
    dinv_kernel<<<(NB * NN + 255) / 256, 256, 0, stream>>>(deg, dinv);
    scan_kernel<<<NB, 1024, 0, stream>>>(deg, offs, cursor);
    fill_kernel<<<edge_grid, 256, 0, stream>>>(ei, flag, cursor, csr);

    dim3 gemm_grid(8 * ((NN + 63) / 64));   // blockIdx&7 = graph (XCD-local)
    dim3 agg_grid(NB * (NN / 4));           // 20000 blocks, 4 waves/block

    // Layer 1: h -> d_out
    gemm_scale<<<gemm_grid, 256, 0, stream>>>(xs, W1, dinv, y);
    aggregate_half<1><<<agg_grid, 256, 0, stream>>>(y, offs, csr, dinv, b1, mask, out, 0);
    aggregate_half<1><<<agg_grid, 256, 0, stream>>>(y, offs, csr, dinv, b1, mask, out, 1);

    // Layer 2: reads h from d_out into y, then overwrites d_out
    gemm_scale<<<gemm_grid, 256, 0, stream>>>(out, W2, dinv, y);
    aggregate_half<2><<<agg_grid, 256, 0, stream>>>(y, offs, csr, dinv, b2, nullptr, out, 0);
    aggregate_half<2><<<agg_grid, 256, 0, stream>>>(y, offs, csr, dinv, b2, nullptr, out, 1);
}

// Round 7
// 538.440 us; speedup vs baseline: 1.1666x; 1.1666x over previous
//
#include <hip/hip_runtime.h>

#define NB 8
#define NN 10000
#define NE 320000
#define NF 128
#define NH 128

// ---------------- ws layout (float/int indices into ws) ----------------
// [0,        80000)    dinv    (NB*NN f32)
// [80000,   160000)    deg     (NB*NN i32)
// [160000,  160016)    flag    (i32 edge-dtype detect + DCE sink)
// [160016, 1440016)    mask    (NN*NH f32: 0.0 or 2.0)
// [1440016, 1520024)   offs    (NB*(NN+1) i32) CSR offsets per graph
// [1520024, 1600024)   cursor  (NB*NN i32)
// [1600024, 4160024)   csr     (NB*NE i32) source rows bucketed by dst
// [4160024, 14400024)  y = (X@W)*dinv[row]  (NB*NN*NH f32)

__device__ __forceinline__ int load_edge(const int* ei, size_t idx, int is64) {
    if (is64) return (int)(((const long long*)ei)[idx]);
    return ei[idx];
}

// Non-temporal variant: streaming edge reads must not evict warmed csr lines.
__device__ __forceinline__ int load_edge_nt(const int* ei, size_t idx, int is64) {
    if (is64) return (int)__builtin_nontemporal_load(((const long long*)ei) + idx);
    return __builtin_nontemporal_load(ei + idx);
}

__global__ void detect_kernel(const int* __restrict__ ei, int* __restrict__ flag) {
    __shared__ int s;
    if (threadIdx.x == 0) s = 1;
    __syncthreads();
    int bad = 0;
    for (int q = threadIdx.x; q < 1024; q += 256)
        if (ei[2 * q + 1] != 0) bad = 1;
    if (bad) atomicAnd(&s, 0);
    __syncthreads();
    if (threadIdx.x == 0) *flag = s;   // 1 => int64 layout
}

// JAX threefry2x32, partitionable path: counter i -> (hi=0, lo=i), key (0,42),
// out = x0 ^ x1; keep <=> MSB==0; scale 2.0 (keep) else 0.0.
__global__ void mask_kernel(float* __restrict__ mask) {
    const unsigned TOT = NN * NH;
    unsigned i = blockIdx.x * 256 + threadIdx.x;
    if (i >= TOT) return;
    const unsigned ks0 = 0u, ks1 = 42u, ks2 = 0x1BD11BDAu ^ 0u ^ 42u;
    unsigned x0 = 0u + ks0;
    unsigned x1 = i + ks1;
#define TFR(r) { x0 += x1; x1 = (x1 << (r)) | (x1 >> (32 - (r))); x1 ^= x0; }
    TFR(13) TFR(15) TFR(26) TFR(6)
    x0 += ks1; x1 += ks2 + 1u;
    TFR(17) TFR(29) TFR(16) TFR(24)
    x0 += ks2; x1 += ks0 + 2u;
    TFR(13) TFR(15) TFR(26) TFR(6)
    x0 += ks0; x1 += ks1 + 3u;
    TFR(17) TFR(29) TFR(16) TFR(24)
    x0 += ks1; x1 += ks2 + 4u;
    TFR(13) TFR(15) TFR(26) TFR(6)
    x0 += ks2; x1 += ks0 + 5u;
#undef TFR
    unsigned bits = x0 ^ x1;
    mask[i] = (bits & 0x80000000u) ? 0.0f : 2.0f;
}

// XCD-local: blockIdx&7 = graph, so each graph's deg (40KB) stays in one L2.
__global__ __launch_bounds__(256) void deg_kernel(const int* __restrict__ ei,
                                                  const int* __restrict__ flag,
                                                  int* __restrict__ deg) {
    int b = blockIdx.x & 7;
    int e = (blockIdx.x >> 3) * 256 + threadIdx.x;
    if (e >= NE) return;
    int is64 = *flag;
    int col = load_edge_nt(ei, (size_t)b * 2 * NE + NE + e, is64);
    atomicAdd(&deg[b * NN + col], 1);
}

__global__ __launch_bounds__(256) void dinv_kernel(const int* __restrict__ deg,
                                                   float* __restrict__ dinv) {
    int i = blockIdx.x * 256 + threadIdx.x;
    if (i >= NB * NN) return;
    dinv[i] = 1.0f / sqrtf((float)(deg[i] + 1));  // +1 self-loop
}

// Exclusive prefix scan of deg per graph -> offs (and cursor copy). 1 block/graph.
__global__ __launch_bounds__(1024) void scan_kernel(const int* __restrict__ deg,
                                                    int* __restrict__ offs,
                                                    int* __restrict__ cursor) {
    int b = blockIdx.x;
    __shared__ int s[1024];
    int t = threadIdx.x;
    int carry = 0;
    for (int c0 = 0; c0 < NN; c0 += 1024) {
        int i = c0 + t;
        int v = (i < NN) ? deg[b * NN + i] : 0;
        s[t] = v;
        __syncthreads();
        int x = v;
        for (int off = 1; off < 1024; off <<= 1) {
            int add = (t >= off) ? s[t - off] : 0;
            __syncthreads();
            x += add;
            s[t] = x;
            __syncthreads();
        }
        int tot = s[1023];
        if (i < NN) {
            int e = carry + x - v;       // exclusive
            offs[b * (NN + 1) + i] = e;
            cursor[b * NN + i] = e;
        }
        carry += tot;
        __syncthreads();
    }
    if (t == 0) offs[b * (NN + 1) + NN] = carry;
}

// Pre-warm: densely READ each graph's csr slice into its XCD's L2 so fill's
// scattered stores HIT (writeback combine) instead of write-through missing.
// blockIdx&7 = graph matches fill's XCD mapping. ~10MB total, ~4us.
__global__ __launch_bounds__(256) void warm_kernel(const int* __restrict__ csr,
                                                   int* __restrict__ sink) {
    int b = blockIdx.x & 7;
    int e4 = ((blockIdx.x >> 3) * 256 + threadIdx.x) * 4;
    if (e4 >= NE) return;
    const int4* p = (const int4*)(csr + (size_t)b * NE + e4);
    int4 v = *p;
    int sum = v.x + v.y + v.z + v.w;
    if (sum == (int)0xdeadbeef) *sink = sum;   // never taken; defeats DCE
}

// Bucket-fill CSR, XCD-local, plain store into warmed lines.
__global__ __launch_bounds__(256) void fill_kernel(const int* __restrict__ ei,
                                                   const int* __restrict__ flag,
                                                   int* __restrict__ cursor,
                                                   int* __restrict__ csr) {
    int b = blockIdx.x & 7;
    int e = (blockIdx.x >> 3) * 256 + threadIdx.x;
    if (e >= NE) return;
    int is64 = *flag;
    size_t base = (size_t)b * 2 * NE;
    int row = load_edge_nt(ei, base + e, is64);
    int col = load_edge_nt(ei, base + NE + e, is64);
    int pos = atomicAdd(&cursor[b * NN + col], 1);
    csr[(size_t)b * NE + pos] = row;
}

// y = (X @ W) * dinv[row].  blockIdx.x&7 = graph (XCD-local), >>3 = row block.
__global__ __launch_bounds__(256) void gemm_scale(const float* __restrict__ X,
                                                  const float* __restrict__ Wm,
                                                  const float* __restrict__ dinv,
                                                  float* __restrict__ y) {
    __shared__ float Xs[64][32];
    __shared__ float Ws[32][128];
    int b = blockIdx.x & 7;
    int row0 = (blockIdx.x >> 3) * 64;
    int t = threadIdx.x;
    int cg = t & 31;
    int rg = t >> 5;
    float acc[8][4] = {};
    const float* Xb = X + (size_t)b * NN * NF;

    for (int k0 = 0; k0 < NF; k0 += 32) {
        for (int q = t; q < 512; q += 256) {
            int r = q >> 3, c4 = q & 7;
            int gr = row0 + r;
            float4 v = make_float4(0.f, 0.f, 0.f, 0.f);
            if (gr < NN) v = *(const float4*)(Xb + (size_t)gr * NF + k0 + c4 * 4);
            *(float4*)&Xs[r][c4 * 4] = v;
        }
        for (int q = t; q < 1024; q += 256) {
            float4 v = *(const float4*)(Wm + k0 * NH + q * 4);
            *(float4*)(&Ws[0][0] + q * 4) = v;
        }
        __syncthreads();
#pragma unroll
        for (int kc = 0; kc < 32; kc += 4) {
            float4 xv[8];
#pragma unroll
            for (int i = 0; i < 8; ++i) xv[i] = *(const float4*)&Xs[rg * 8 + i][kc];
#pragma unroll
            for (int j = 0; j < 4; ++j) {
                float4 w = *(const float4*)&Ws[kc + j][cg * 4];
#pragma unroll
                for (int i = 0; i < 8; ++i) {
                    float xsv = (j == 0) ? xv[i].x : (j == 1) ? xv[i].y
                              : (j == 2) ? xv[i].z : xv[i].w;
                    acc[i][0] = fmaf(xsv, w.x, acc[i][0]);
                    acc[i][1] = fmaf(xsv, w.y, acc[i][1]);
                    acc[i][2] = fmaf(xsv, w.z, acc[i][2]);
                    acc[i][3] = fmaf(xsv, w.w, acc[i][3]);
                }
            }
        }
        __syncthreads();
    }
#pragma unroll
    for (int i = 0; i < 8; ++i) {
        int gr = row0 + rg * 8 + i;
        if (gr >= NN) continue;
        float d = dinv[b * NN + gr];
        float4 v = make_float4(acc[i][0] * d, acc[i][1] * d, acc[i][2] * d, acc[i][3] * d);
        *(float4*)(y + ((size_t)b * NN + gr) * NH + cg * 4) = v;
    }
}

// Gather-reduce over one 64-feature half. One wave per node.
// 4 edges/iter: sub = lane>>4 picks the edge, 16 lanes x float4 = 64 feats.
// blockIdx%8 = graph -> per-(graph,half) working set 2.56MB resident in XCD L2.
template<int LAYER>
__global__ __launch_bounds__(256) void aggregate_half(const float* __restrict__ y,
                                                      const int* __restrict__ offs,
                                                      const int* __restrict__ csr,
                                                      const float* __restrict__ dinv,
                                                      const float* __restrict__ bias,
                                                      const float* __restrict__ mask,
                                                      float* __restrict__ out,
                                                      int half) {
    int b = blockIdx.x & 7;
    int w = threadIdx.x >> 6;
    int n = (blockIdx.x >> 3) * 4 + w;       // 2500*4 = 10000 exact
    int lane = threadIdx.x & 63;
    int sub = lane >> 4;                      // which edge of the group of 4
    int f4 = (lane & 15) * 4 + half * 64;     // feature quad
    const float* yb = y + (size_t)b * NN * NH;
    int o0 = offs[b * (NN + 1) + n];
    int o1 = offs[b * (NN + 1) + n + 1];
    float4 acc = make_float4(0.f, 0.f, 0.f, 0.f);
    if (sub == 0) acc = *(const float4*)(yb + (size_t)n * NH + f4);   // self-loop once
    const int* csrb = csr + (size_t)b * NE;
    for (int base = o0; base < o1; base += 64) {
        int m = o1 - base; if (m > 64) m = 64;
        int r = (lane < m) ? csrb[base + lane] : 0;
        int mp = m & ~3;
#pragma unroll 4
        for (int jj = 0; jj < mp; jj += 4) {
            int row = __shfl(r, jj + sub);
            float4 v = *(const float4*)(yb + (size_t)row * NH + f4);
            acc.x += v.x; acc.y += v.y; acc.z += v.z; acc.w += v.w;
        }
        if (mp < m) {                          // wave-uniform tail (1..3 edges)
            int rem = m - mp;
            int row = __shfl(r, mp + (sub < rem ? sub : 0));
            float4 v = *(const float4*)(yb + (size_t)row * NH + f4);
            if (sub < rem) { acc.x += v.x; acc.y += v.y; acc.z += v.z; acc.w += v.w; }
        }
    }
    // combine the 4 edge-subsets (lanes L, L+16, L+32, L+48 share features)
    acc.x += __shfl_xor(acc.x, 16); acc.y += __shfl_xor(acc.y, 16);
    acc.z += __shfl_xor(acc.z, 16); acc.w += __shfl_xor(acc.w, 16);
    acc.x += __shfl_xor(acc.x, 32); acc.y += __shfl_xor(acc.y, 32);
    acc.z += __shfl_xor(acc.z, 32); acc.w += __shfl_xor(acc.w, 32);
    if (lane < 16) {
        float d = dinv[b * NN + n];
        float4 bi = *(const float4*)(bias + f4);
        float4 o;
        o.x = fmaf(d, acc.x, bi.x);
        o.y = fmaf(d, acc.y, bi.y);
        o.z = fmaf(d, acc.z, bi.z);
        o.w = fmaf(d, acc.w, bi.w);
        if (LAYER == 1) {
            float4 m4 = *(const float4*)(mask + (size_t)n * NH + f4);
            o.x = fmaxf(o.x, 0.f) * m4.x;
            o.y = fmaxf(o.y, 0.f) * m4.y;
            o.z = fmaxf(o.z, 0.f) * m4.z;
            o.w = fmaxf(o.w, 0.f) * m4.w;
        }
        *(float4*)(out + ((size_t)b * NN + n) * NH + f4) = o;
    }
}

extern "C" void kernel_launch(void* const* d_in, const int* in_sizes, int n_in,
                              void* d_out, int out_size, void* d_ws, size_t ws_size,
                              hipStream_t stream) {
    const float* xs = (const float*)d_in[0];
    const int*   ei = (const int*)d_in[1];
    const float* W1 = (const float*)d_in[2];
    const float* b1 = (const float*)d_in[3];
    const float* W2 = (const float*)d_in[4];
    const float* b2 = (const float*)d_in[5];
    float* out = (float*)d_out;

    float* ws     = (float*)d_ws;
    float* dinv   = ws;
    int*   deg    = (int*)(ws + 80000);
    int*   flag   = (int*)(ws + 160000);
    float* mask   = ws + 160016;
    int*   offs   = (int*)(ws + 1440016);
    int*   cursor = (int*)(ws + 1520024);
    int*   csr    = (int*)(ws + 1600024);
    float* y      = ws + 4160024;

    dim3 edge_grid(8 * ((NE + 255) / 256));       // blockIdx&7 = graph (XCD-local)
    dim3 warm_grid(8 * ((NE + 1023) / 1024));     // 4 ints per thread

    hipMemsetAsync(deg, 0, (size_t)NB * NN * sizeof(int), stream);
    detect_kernel<<<1, 256, 0, stream>>>(ei, flag);
    mask_kernel<<<(NN * NH + 255) / 256, 256, 0, stream>>>(mask);
    deg_kernel<<<edge_grid, 256, 0, stream>>>(ei, flag, deg);
    dinv_kernel<<<(NB * NN + 255) / 256, 256, 0, stream>>>(deg, dinv);
    scan_kernel<<<NB, 1024, 0, stream>>>(deg, offs, cursor);
    warm_kernel<<<warm_grid, 256, 0, stream>>>(csr, flag + 1);
    fill_kernel<<<edge_grid, 256, 0, stream>>>(ei, flag, cursor, csr);

    dim3 gemm_grid(8 * ((NN + 63) / 64));   // blockIdx&7 = graph (XCD-local)
    dim3 agg_grid(NB * (NN / 4));           // 20000 blocks, 4 waves/block

    // Layer 1: h -> d_out
    gemm_scale<<<gemm_grid, 256, 0, stream>>>(xs, W1, dinv, y);
    aggregate_half<1><<<agg_grid, 256, 0, stream>>>(y, offs, csr, dinv, b1, mask, out, 0);
    aggregate_half<1><<<agg_grid, 256, 0, stream>>>(y, offs, csr, dinv, b1, mask, out, 1);

    // Layer 2: reads h from d_out into y, then overwrites d_out
    gemm_scale<<<gemm_grid, 256, 0, stream>>>(out, W2, dinv, y);
    aggregate_half<2><<<agg_grid, 256, 0, stream>>>(y, offs, csr, dinv, b2, nullptr, out, 0);
    aggregate_half<2><<<agg_grid, 256, 0, stream>>>(y, offs, csr, dinv, b2, nullptr, out, 1);
}

// Round 8
// 523.660 us; speedup vs baseline: 1.1996x; 1.0282x over previous
//
#include <hip/hip_runtime.h>

#define NB 8
#define NN 10000
#define NE 320000
#define NF 128
#define NH 128

// ---------------- ws layout (float/int indices into ws) ----------------
// [0,        80000)    dinv    (NB*NN f32)
// [80000,   160000)    deg     (NB*NN i32)
// [160000,  160016)    flag    (i32 edge-dtype detect)
// [160016, 1440016)    mask    (NN*NH f32: 0.0 or 2.0)
// [1440016, 1520024)   offs    (NB*(NN+1) i32) CSR offsets per graph
// [1520024, 1600024)   cursor  (NB*NN i32)
// [1600024, 4160024)   csr     (NB*NE i32) source rows bucketed by dst
// [4160024, 14400024)  y = (X@W)*dinv[row]  (NB*NN*NH f32)

__device__ __forceinline__ int load_edge_nt(const int* ei, size_t idx, int is64) {
    if (is64) return (int)__builtin_nontemporal_load(((const long long*)ei) + idx);
    return __builtin_nontemporal_load(ei + idx);
}

__global__ void detect_kernel(const int* __restrict__ ei, int* __restrict__ flag) {
    __shared__ int s;
    if (threadIdx.x == 0) s = 1;
    __syncthreads();
    int bad = 0;
    for (int q = threadIdx.x; q < 1024; q += 256)
        if (ei[2 * q + 1] != 0) bad = 1;
    if (bad) atomicAnd(&s, 0);
    __syncthreads();
    if (threadIdx.x == 0) *flag = s;   // 1 => int64 layout
}

// JAX threefry2x32, partitionable path: counter i -> (hi=0, lo=i), key (0,42),
// out = x0 ^ x1; keep <=> MSB==0; scale 2.0 (keep) else 0.0.
__global__ void mask_kernel(float* __restrict__ mask) {
    const unsigned TOT = NN * NH;
    unsigned i = blockIdx.x * 256 + threadIdx.x;
    if (i >= TOT) return;
    const unsigned ks0 = 0u, ks1 = 42u, ks2 = 0x1BD11BDAu ^ 0u ^ 42u;
    unsigned x0 = 0u + ks0;
    unsigned x1 = i + ks1;
#define TFR(r) { x0 += x1; x1 = (x1 << (r)) | (x1 >> (32 - (r))); x1 ^= x0; }
    TFR(13) TFR(15) TFR(26) TFR(6)
    x0 += ks1; x1 += ks2 + 1u;
    TFR(17) TFR(29) TFR(16) TFR(24)
    x0 += ks2; x1 += ks0 + 2u;
    TFR(13) TFR(15) TFR(26) TFR(6)
    x0 += ks0; x1 += ks1 + 3u;
    TFR(17) TFR(29) TFR(16) TFR(24)
    x0 += ks1; x1 += ks2 + 4u;
    TFR(13) TFR(15) TFR(26) TFR(6)
    x0 += ks2; x1 += ks0 + 5u;
#undef TFR
    unsigned bits = x0 ^ x1;
    mask[i] = (bits & 0x80000000u) ? 0.0f : 2.0f;
}

// XCD-local: blockIdx&7 = graph, so each graph's deg (40KB) stays in one L2.
__global__ __launch_bounds__(256) void deg_kernel(const int* __restrict__ ei,
                                                  const int* __restrict__ flag,
                                                  int* __restrict__ deg) {
    int b = blockIdx.x & 7;
    int e = (blockIdx.x >> 3) * 256 + threadIdx.x;
    if (e >= NE) return;
    int is64 = *flag;
    int col = load_edge_nt(ei, (size_t)b * 2 * NE + NE + e, is64);
    atomicAdd(&deg[b * NN + col], 1);
}

__global__ __launch_bounds__(256) void dinv_kernel(const int* __restrict__ deg,
                                                   float* __restrict__ dinv) {
    int i = blockIdx.x * 256 + threadIdx.x;
    if (i >= NB * NN) return;
    dinv[i] = 1.0f / sqrtf((float)(deg[i] + 1));  // +1 self-loop
}

// Exclusive prefix scan of deg per graph -> offs (and cursor copy). 1 block/graph.
__global__ __launch_bounds__(1024) void scan_kernel(const int* __restrict__ deg,
                                                    int* __restrict__ offs,
                                                    int* __restrict__ cursor) {
    int b = blockIdx.x;
    __shared__ int s[1024];
    int t = threadIdx.x;
    int carry = 0;
    for (int c0 = 0; c0 < NN; c0 += 1024) {
        int i = c0 + t;
        int v = (i < NN) ? deg[b * NN + i] : 0;
        s[t] = v;
        __syncthreads();
        int x = v;
        for (int off = 1; off < 1024; off <<= 1) {
            int add = (t >= off) ? s[t - off] : 0;
            __syncthreads();
            x += add;
            s[t] = x;
            __syncthreads();
        }
        int tot = s[1023];
        if (i < NN) {
            int e = carry + x - v;       // exclusive
            offs[b * (NN + 1) + i] = e;
            cursor[b * NN + i] = e;
        }
        carry += tot;
        __syncthreads();
    }
    if (t == 0) offs[b * (NN + 1) + NN] = carry;
}

// Bucket-fill CSR, XCD-local. HW model (r6/r7 measured): scattered dword
// stores write through at ~32-40B granularity regardless of L2 residency;
// atomics and pre-warming don't enable combining. ~100MB writes, ~111us.
__global__ __launch_bounds__(256) void fill_kernel(const int* __restrict__ ei,
                                                   const int* __restrict__ flag,
                                                   int* __restrict__ cursor,
                                                   int* __restrict__ csr) {
    int b = blockIdx.x & 7;
    int e = (blockIdx.x >> 3) * 256 + threadIdx.x;
    if (e >= NE) return;
    int is64 = *flag;
    size_t base = (size_t)b * 2 * NE;
    int row = load_edge_nt(ei, base + e, is64);
    int col = load_edge_nt(ei, base + NE + e, is64);
    int pos = atomicAdd(&cursor[b * NN + col], 1);
    csr[(size_t)b * NE + pos] = row;
}

// y = (X @ W) * dinv[row].  blockIdx.x&7 = graph (XCD-local), >>3 = row block.
__global__ __launch_bounds__(256) void gemm_scale(const float* __restrict__ X,
                                                  const float* __restrict__ Wm,
                                                  const float* __restrict__ dinv,
                                                  float* __restrict__ y) {
    __shared__ float Xs[64][32];
    __shared__ float Ws[32][128];
    int b = blockIdx.x & 7;
    int row0 = (blockIdx.x >> 3) * 64;
    int t = threadIdx.x;
    int cg = t & 31;
    int rg = t >> 5;
    float acc[8][4] = {};
    const float* Xb = X + (size_t)b * NN * NF;

    for (int k0 = 0; k0 < NF; k0 += 32) {
        for (int q = t; q < 512; q += 256) {
            int r = q >> 3, c4 = q & 7;
            int gr = row0 + r;
            float4 v = make_float4(0.f, 0.f, 0.f, 0.f);
            if (gr < NN) v = *(const float4*)(Xb + (size_t)gr * NF + k0 + c4 * 4);
            *(float4*)&Xs[r][c4 * 4] = v;
        }
        for (int q = t; q < 1024; q += 256) {
            float4 v = *(const float4*)(Wm + k0 * NH + q * 4);
            *(float4*)(&Ws[0][0] + q * 4) = v;
        }
        __syncthreads();
#pragma unroll
        for (int kc = 0; kc < 32; kc += 4) {
            float4 xv[8];
#pragma unroll
            for (int i = 0; i < 8; ++i) xv[i] = *(const float4*)&Xs[rg * 8 + i][kc];
#pragma unroll
            for (int j = 0; j < 4; ++j) {
                float4 w = *(const float4*)&Ws[kc + j][cg * 4];
#pragma unroll
                for (int i = 0; i < 8; ++i) {
                    float xsv = (j == 0) ? xv[i].x : (j == 1) ? xv[i].y
                              : (j == 2) ? xv[i].z : xv[i].w;
                    acc[i][0] = fmaf(xsv, w.x, acc[i][0]);
                    acc[i][1] = fmaf(xsv, w.y, acc[i][1]);
                    acc[i][2] = fmaf(xsv, w.z, acc[i][2]);
                    acc[i][3] = fmaf(xsv, w.w, acc[i][3]);
                }
            }
        }
        __syncthreads();
    }
#pragma unroll
    for (int i = 0; i < 8; ++i) {
        int gr = row0 + rg * 8 + i;
        if (gr >= NN) continue;
        float d = dinv[b * NN + gr];
        float4 v = make_float4(acc[i][0] * d, acc[i][1] * d, acc[i][2] * d, acc[i][3] * d);
        *(float4*)(y + ((size_t)b * NN + gr) * NH + cg * 4) = v;
    }
}

__device__ __forceinline__ int chunk_load(const int* __restrict__ csrb,
                                          int base, int o1, int lane) {
    if (base >= o1) return 0;
    int m = o1 - base; if (m > 64) m = 64;
    return (lane < m) ? csrb[base + lane] : 0;
}

// Gather-reduce over one 64-feature half. One wave per TWO nodes (idx, idx+5000):
// two independent csr/y load streams per wave overlap their L2 latencies
// (round-3 profile: VALUBusy 24%, HBM 23% -> latency-chain bound, not BW).
// 4 edges/iter per stream: sub = lane>>4, 16 lanes x float4 = 64 feats.
// blockIdx&7 = graph -> per-(graph,half) working set 2.56MB resident in XCD L2.
template<int LAYER>
__global__ __launch_bounds__(256) void aggregate_half(const float* __restrict__ y,
                                                      const int* __restrict__ offs,
                                                      const int* __restrict__ csr,
                                                      const float* __restrict__ dinv,
                                                      const float* __restrict__ bias,
                                                      const float* __restrict__ mask,
                                                      float* __restrict__ out,
                                                      int half) {
    int b = blockIdx.x & 7;
    int w = threadIdx.x >> 6;
    int idx = (blockIdx.x >> 3) * 4 + w;     // [0, 5000)
    int n0 = idx, n1 = idx + 5000;
    int lane = threadIdx.x & 63;
    int sub = lane >> 4;
    int f4 = (lane & 15) * 4 + half * 64;
    const float* yb = y + (size_t)b * NN * NH;

    // self-loop loads first (independent of offs chain)
    float4 acc0 = make_float4(0.f, 0.f, 0.f, 0.f);
    float4 acc1 = make_float4(0.f, 0.f, 0.f, 0.f);
    if (sub == 0) {
        acc0 = *(const float4*)(yb + (size_t)n0 * NH + f4);
        acc1 = *(const float4*)(yb + (size_t)n1 * NH + f4);
    }

    const int* ob = offs + b * (NN + 1);
    int o0a = ob[n0], o1a = ob[n0 + 1];
    int o0b = ob[n1], o1b = ob[n1 + 1];
    const int* csrb = csr + (size_t)b * NE;

    int ba = o0a, bb = o0b;
    int ra = chunk_load(csrb, ba, o1a, lane);
    int rb = chunk_load(csrb, bb, o1b, lane);

#define PROC(r_, m_, acc_) { \
    int mp = (m_) & ~3; \
    _Pragma("unroll 4") \
    for (int jj = 0; jj < mp; jj += 4) { \
        int row = __shfl((r_), jj + sub); \
        float4 v = *(const float4*)(yb + (size_t)row * NH + f4); \
        acc_.x += v.x; acc_.y += v.y; acc_.z += v.z; acc_.w += v.w; \
    } \
    if (mp < (m_)) { \
        int rem = (m_) - mp; \
        int row = __shfl((r_), mp + (sub < rem ? sub : 0)); \
        float4 v = *(const float4*)(yb + (size_t)row * NH + f4); \
        if (sub < rem) { acc_.x += v.x; acc_.y += v.y; acc_.z += v.z; acc_.w += v.w; } \
    } \
}

    while (ba < o1a || bb < o1b) {
        int ma = o1a - ba; ma = ma < 0 ? 0 : (ma > 64 ? 64 : ma);
        int mb = o1b - bb; mb = mb < 0 ? 0 : (mb > 64 ? 64 : mb);
        int ran = chunk_load(csrb, ba + 64, o1a, lane);   // prefetch next chunks
        int rbn = chunk_load(csrb, bb + 64, o1b, lane);
        PROC(ra, ma, acc0);
        PROC(rb, mb, acc1);
        ra = ran; rb = rbn; ba += 64; bb += 64;
    }
#undef PROC

    // combine the 4 edge-subsets (lanes L, L+16, L+32, L+48 share features)
    acc0.x += __shfl_xor(acc0.x, 16); acc0.y += __shfl_xor(acc0.y, 16);
    acc0.z += __shfl_xor(acc0.z, 16); acc0.w += __shfl_xor(acc0.w, 16);
    acc0.x += __shfl_xor(acc0.x, 32); acc0.y += __shfl_xor(acc0.y, 32);
    acc0.z += __shfl_xor(acc0.z, 32); acc0.w += __shfl_xor(acc0.w, 32);
    acc1.x += __shfl_xor(acc1.x, 16); acc1.y += __shfl_xor(acc1.y, 16);
    acc1.z += __shfl_xor(acc1.z, 16); acc1.w += __shfl_xor(acc1.w, 16);
    acc1.x += __shfl_xor(acc1.x, 32); acc1.y += __shfl_xor(acc1.y, 32);
    acc1.z += __shfl_xor(acc1.z, 32); acc1.w += __shfl_xor(acc1.w, 32);

    if (lane < 16) {
        float4 bi = *(const float4*)(bias + f4);
#pragma unroll
        for (int s2 = 0; s2 < 2; ++s2) {
            int n = s2 ? n1 : n0;
            float4 a = s2 ? acc1 : acc0;
            float d = dinv[b * NN + n];
            float4 o;
            o.x = fmaf(d, a.x, bi.x);
            o.y = fmaf(d, a.y, bi.y);
            o.z = fmaf(d, a.z, bi.z);
            o.w = fmaf(d, a.w, bi.w);
            if (LAYER == 1) {
                float4 m4 = *(const float4*)(mask + (size_t)n * NH + f4);
                o.x = fmaxf(o.x, 0.f) * m4.x;
                o.y = fmaxf(o.y, 0.f) * m4.y;
                o.z = fmaxf(o.z, 0.f) * m4.z;
                o.w = fmaxf(o.w, 0.f) * m4.w;
            }
            *(float4*)(out + ((size_t)b * NN + n) * NH + f4) = o;
        }
    }
}

extern "C" void kernel_launch(void* const* d_in, const int* in_sizes, int n_in,
                              void* d_out, int out_size, void* d_ws, size_t ws_size,
                              hipStream_t stream) {
    const float* xs = (const float*)d_in[0];
    const int*   ei = (const int*)d_in[1];
    const float* W1 = (const float*)d_in[2];
    const float* b1 = (const float*)d_in[3];
    const float* W2 = (const float*)d_in[4];
    const float* b2 = (const float*)d_in[5];
    float* out = (float*)d_out;

    float* ws     = (float*)d_ws;
    float* dinv   = ws;
    int*   deg    = (int*)(ws + 80000);
    int*   flag   = (int*)(ws + 160000);
    float* mask   = ws + 160016;
    int*   offs   = (int*)(ws + 1440016);
    int*   cursor = (int*)(ws + 1520024);
    int*   csr    = (int*)(ws + 1600024);
    float* y      = ws + 4160024;

    dim3 edge_grid(8 * ((NE + 255) / 256));       // blockIdx&7 = graph (XCD-local)

    hipMemsetAsync(deg, 0, (size_t)NB * NN * sizeof(int), stream);
    detect_kernel<<<1, 256, 0, stream>>>(ei, flag);
    mask_kernel<<<(NN * NH + 255) / 256, 256, 0, stream>>>(mask);
    deg_kernel<<<edge_grid, 256, 0, stream>>>(ei, flag, deg);
    dinv_kernel<<<(NB * NN + 255) / 256, 256, 0, stream>>>(deg, dinv);
    scan_kernel<<<NB, 1024, 0, stream>>>(deg, offs, cursor);
    fill_kernel<<<edge_grid, 256, 0, stream>>>(ei, flag, cursor, csr);

    dim3 gemm_grid(8 * ((NN + 63) / 64));   // blockIdx&7 = graph (XCD-local)
    dim3 agg_grid(NB * (5000 / 4));         // 10000 blocks, 4 waves x 2 nodes each

    // Layer 1: h -> d_out
    gemm_scale<<<gemm_grid, 256, 0, stream>>>(xs, W1, dinv, y);
    aggregate_half<1><<<agg_grid, 256, 0, stream>>>(y, offs, csr, dinv, b1, mask, out, 0);
    aggregate_half<1><<<agg_grid, 256, 0, stream>>>(y, offs, csr, dinv, b1, mask, out, 1);

    // Layer 2: reads h from d_out into y, then overwrites d_out
    gemm_scale<<<gemm_grid, 256, 0, stream>>>(out, W2, dinv, y);
    aggregate_half<2><<<agg_grid, 256, 0, stream>>>(y, offs, csr, dinv, b2, nullptr, out, 0);
    aggregate_half<2><<<agg_grid, 256, 0, stream>>>(y, offs, csr, dinv, b2, nullptr, out, 1);
}